// Round 7
// baseline (799.204 us; speedup 1.0000x reference)
//
#include <hip/hip_runtime.h>

#define N_NODES   100000
#define N_EDGES   1600000
#define EDGE_DIM  32
#define NODE_DIM  128
#define K1        192    // rec32 + send32 + node128 (glob folded into b1_eff)
#define HIDDEN    256
#define OUT_DIM   128

typedef float  f32x4   __attribute__((ext_vector_type(4)));
typedef short  short8  __attribute__((ext_vector_type(8)));
typedef unsigned short ushort8 __attribute__((ext_vector_type(8)));

// ws layout (4-byte words): feats + weights only (~13 MB)
#define WS_FEATS_W 0                         // ushort[100000*64]
#define WS_W1T_W   3200000                   // ushort[256*192]
#define WS_W2T_W   (WS_W1T_W + 24576)        // ushort[128*256]
#define WS_B1E_W   (WS_W2T_W + 16384)        // float[256]

__device__ __forceinline__ unsigned short f2bf(float f) {
    unsigned int u = __float_as_uint(f);
    return (unsigned short)((u + 0x7fffu + ((u >> 16) & 1u)) >> 16);   // RNE
}

// ---------------------------------------------------------------------------
// Weight prep: W1T[n][k] (k<192), W2T[o][k], b1_eff = b1 + glob @ W1[192:224]
// ---------------------------------------------------------------------------
__global__ __launch_bounds__(256) void wcvt_kernel(
    const float* __restrict__ W1, const float* __restrict__ W2,
    const float* __restrict__ b1, const float* __restrict__ glob,
    unsigned short* __restrict__ W1T, unsigned short* __restrict__ W2T,
    float* __restrict__ b1e)
{
    int id = blockIdx.x * 256 + threadIdx.x;
    if (id < K1 * HIDDEN) {                              // 49152
        int n = id / K1, k = id - n * K1;
        W1T[id] = f2bf(W1[(size_t)k * HIDDEN + n]);
    } else if (id < K1 * HIDDEN + HIDDEN * OUT_DIM) {    // +32768
        int id2 = id - K1 * HIDDEN;
        int o = id2 / HIDDEN, k = id2 - o * HIDDEN;
        W2T[id2] = f2bf(W2[(size_t)k * OUT_DIM + o]);
    } else if (id < K1 * HIDDEN + HIDDEN * OUT_DIM + HIDDEN) {
        int n = id - (K1 * HIDDEN + HIDDEN * OUT_DIM);
        float s = b1[n];
        #pragma unroll
        for (int j = 0; j < 32; ++j)
            s += glob[j] * W1[(size_t)(K1 + j) * HIDDEN + n];
        b1e[n] = s;
    }
}

// ---------------------------------------------------------------------------
// Owner-computes aggregation. Block b < 98: receivers for nodes
// [b*1024, b*1024+1024); block b >= 98: senders. Accumulators in LDS
// (fp32, stride 33 to de-bank). Each of 16 waves scans a strided slice of
// the key array, compacts matches into a per-wave LDS ring (ballot/mbcnt),
// and drains 8 edges at a time (8 lanes/edge, coalesced 128B row reads,
// LDS float atomics). No global atomics anywhere.
// ---------------------------------------------------------------------------
#define NB      1024
#define NBLK    98            // ceil(100000/1024)
#define AGG_T   1024
#define AGG_W   16
#define ASTRIDE 33

__global__ __launch_bounds__(1024) void agg_kernel(
    const float* __restrict__ edge,
    const int*   __restrict__ rcv,
    const int*   __restrict__ snd,
    unsigned short* __restrict__ feats_bf)
{
    __shared__ float        acc[NB * ASTRIDE];   // 132 KB
    __shared__ unsigned int q[AGG_W][256];       // 16 KB ring buffers

    const int tid  = threadIdx.x;
    const int dir  = (blockIdx.x >= NBLK) ? 1 : 0;
    const int blk  = dir ? (blockIdx.x - NBLK) : blockIdx.x;
    const int lo   = blk * NB;
    const int rangeN = min(NB, N_NODES - lo);
    const int* __restrict__ key = dir ? snd : rcv;
    const int cb   = dir ? 32 : 0;

    for (int i = tid; i < NB * ASTRIDE; i += AGG_T) acc[i] = 0.f;
    __syncthreads();

    const int wave = tid >> 6;
    const int lane = tid & 63;
    const int sub  = lane & 7;
    const float4* __restrict__ ef4 = (const float4*)edge;

    unsigned qc = 0, qdone = 0;   // wave-uniform

    const int ITER = (N_EDGES + AGG_T * 4 - 1) / (AGG_T * 4);   // 391
    for (int i = 0; i < ITER; ++i) {
        int base = ((i * AGG_W + wave) * 64 + lane) * 4;
        int4 k4 = make_int4(-1, -1, -1, -1);
        if (base < N_EDGES) k4 = *(const int4*)&key[base];
        #pragma unroll
        for (int j = 0; j < 4; ++j) {
            int kk = (&k4.x)[j];
            unsigned local = (unsigned)(kk - lo);
            bool m = local < (unsigned)rangeN;
            unsigned long long mask = __ballot(m);
            if (mask) {
                unsigned idx = __builtin_amdgcn_mbcnt_hi(
                    (unsigned)(mask >> 32),
                    __builtin_amdgcn_mbcnt_lo((unsigned)mask, 0));
                if (m)
                    q[wave][(qc + idx) & 255] = (local << 21) | (unsigned)(base + j);
                qc += (unsigned)__popcll(mask);
                while (qc - qdone >= 8) {
                    unsigned pk  = q[wave][(qdone + (lane >> 3)) & 255];
                    unsigned nl  = pk >> 21;
                    unsigned eid = pk & 0x1FFFFFu;
                    float4 v = ef4[(size_t)eid * 8 + sub];
                    float* a = &acc[nl * ASTRIDE + sub * 4];
                    atomicAdd(a + 0, v.x);
                    atomicAdd(a + 1, v.y);
                    atomicAdd(a + 2, v.z);
                    atomicAdd(a + 3, v.w);
                    qdone += 8;
                }
            }
        }
    }
    // final drain (<8 left per wave)
    {
        unsigned rem = qc - qdone;
        if ((unsigned)(lane >> 3) < rem) {
            unsigned pk  = q[wave][(qdone + (lane >> 3)) & 255];
            unsigned nl  = pk >> 21;
            unsigned eid = pk & 0x1FFFFFu;
            float4 v = ef4[(size_t)eid * 8 + sub];
            float* a = &acc[nl * ASTRIDE + sub * 4];
            atomicAdd(a + 0, v.x);
            atomicAdd(a + 1, v.y);
            atomicAdd(a + 2, v.z);
            atomicAdd(a + 3, v.w);
        }
    }
    __syncthreads();

    // writeback: rangeN nodes x 16 packed bf16x2 words
    for (int idx2 = tid; idx2 < rangeN * 16; idx2 += AGG_T) {
        int n = idx2 >> 4, l = idx2 & 15;
        float x = acc[n * ASTRIDE + l * 2];
        float y = acc[n * ASTRIDE + l * 2 + 1];
        unsigned pk = (unsigned)f2bf(x) | ((unsigned)f2bf(y) << 16);
        *(unsigned*)&feats_bf[(size_t)(lo + n) * 64 + cb + l * 2] = pk;
    }
}

// ---------------------------------------------------------------------------
// Fused GEMM1+GEMM2: 64 nodes/block, 512 threads (8 waves).
// Wave w: GEMM1 h-cols [32w,32w+32) (W1 frags in regs), GEMM2 out-cols
// [16w,16w+16) (W2 frags in regs). A and h in XOR-swizzled LDS (bf16).
// ---------------------------------------------------------------------------
__global__ __launch_bounds__(512) void gemm12_kernel(
    const unsigned short* __restrict__ feats_bf,
    const float* __restrict__ node,
    const unsigned short* __restrict__ W1T,
    const float* __restrict__ b1e,
    const unsigned short* __restrict__ W2T,
    const float* __restrict__ b2,
    float*       __restrict__ out)
{
    __shared__ unsigned short sA[64 * K1];       // 24 KB
    __shared__ unsigned short sH[64 * HIDDEN];   // 32 KB

    const int tid  = threadIdx.x;
    const int base = blockIdx.x * 64;

    for (int idx = tid; idx < 64 * 24; idx += 512) {
        int row = idx / 24;
        int c   = idx - row * 24;
        int g   = base + row; if (g >= N_NODES) g = N_NODES - 1;
        ushort8 r;
        if (c < 8) {
            r = *(const ushort8*)&feats_bf[(size_t)g * 64 + c * 8];
        } else {
            const float* np = &node[(size_t)g * NODE_DIM + (c - 8) * 8];
            float4 v0 = *(const float4*)np;
            float4 v1 = *(const float4*)(np + 4);
            r[0] = f2bf(v0.x); r[1] = f2bf(v0.y); r[2] = f2bf(v0.z); r[3] = f2bf(v0.w);
            r[4] = f2bf(v1.x); r[5] = f2bf(v1.y); r[6] = f2bf(v1.z); r[7] = f2bf(v1.w);
        }
        *(ushort8*)&sA[row * K1 + ((c ^ (row & 7)) << 3)] = r;
    }
    __syncthreads();

    const int wave = tid >> 6;
    const int lane = tid & 63;
    const int lm   = lane & 15;
    const int lk   = lane >> 4;

    short8 w1f[2][6];
    #pragma unroll
    for (int j = 0; j < 2; ++j) {
        int nt = 2 * wave + j;
        #pragma unroll
        for (int k = 0; k < 6; ++k)
            w1f[j][k] = *(const short8*)&W1T[(size_t)(nt * 16 + lm) * K1 + k * 32 + lk * 8];
    }

    f32x4 acc1[4][2];
    {
        float bv0 = b1e[(2 * wave) * 16 + lm];
        float bv1 = b1e[(2 * wave + 1) * 16 + lm];
        #pragma unroll
        for (int m = 0; m < 4; ++m) {
            acc1[m][0] = (f32x4){bv0, bv0, bv0, bv0};
            acc1[m][1] = (f32x4){bv1, bv1, bv1, bv1};
        }
    }

    #pragma unroll
    for (int k = 0; k < 6; ++k) {
        #pragma unroll
        for (int m = 0; m < 4; ++m) {
            int row   = m * 16 + lm;
            int chunk = k * 4 + lk;
            short8 af = *(const short8*)&sA[row * K1 + ((chunk ^ (row & 7)) << 3)];
            acc1[m][0] = __builtin_amdgcn_mfma_f32_16x16x32_bf16(af, w1f[0][k], acc1[m][0], 0, 0, 0);
            acc1[m][1] = __builtin_amdgcn_mfma_f32_16x16x32_bf16(af, w1f[1][k], acc1[m][1], 0, 0, 0);
        }
    }

    #pragma unroll
    for (int m = 0; m < 4; ++m) {
        #pragma unroll
        for (int j = 0; j < 2; ++j) {
            int col   = (2 * wave + j) * 16 + lm;
            int chunk = col >> 3;
            int cin   = col & 7;
            #pragma unroll
            for (int r = 0; r < 4; ++r) {
                int rowl = m * 16 + lk * 4 + r;
                float v = fmaxf(acc1[m][j][r], 0.0f);
                sH[rowl * HIDDEN + ((chunk ^ (rowl & 7)) << 3) + cin] = f2bf(v);
            }
        }
    }

    short8 w2f[8];
    #pragma unroll
    for (int k = 0; k < 8; ++k)
        w2f[k] = *(const short8*)&W2T[(size_t)(wave * 16 + lm) * HIDDEN + k * 32 + lk * 8];

    f32x4 acc2[4];
    {
        float bv = b2[wave * 16 + lm];
        #pragma unroll
        for (int m = 0; m < 4; ++m) acc2[m] = (f32x4){bv, bv, bv, bv};
    }
    __syncthreads();

    #pragma unroll
    for (int k = 0; k < 8; ++k) {
        #pragma unroll
        for (int m = 0; m < 4; ++m) {
            int row   = m * 16 + lm;
            int chunk = k * 4 + lk;
            short8 hf = *(const short8*)&sH[row * HIDDEN + ((chunk ^ (row & 7)) << 3)];
            acc2[m] = __builtin_amdgcn_mfma_f32_16x16x32_bf16(hf, w2f[k], acc2[m], 0, 0, 0);
        }
    }

    #pragma unroll
    for (int m = 0; m < 4; ++m) {
        #pragma unroll
        for (int r = 0; r < 4; ++r) {
            int grow = base + m * 16 + lk * 4 + r;
            if (grow < N_NODES)
                out[(size_t)grow * OUT_DIM + wave * 16 + lm] = acc2[m][r];
        }
    }
}

extern "C" void kernel_launch(void* const* d_in, const int* in_sizes, int n_in,
                              void* d_out, int out_size, void* d_ws, size_t ws_size,
                              hipStream_t stream) {
    const float* edge = (const float*)d_in[0];
    const int*   snd  = (const int*)  d_in[1];
    const int*   rcv  = (const int*)  d_in[2];
    const float* node = (const float*)d_in[3];
    const float* glob = (const float*)d_in[4];
    const float* W1   = (const float*)d_in[5];
    const float* b1   = (const float*)d_in[6];
    const float* W2   = (const float*)d_in[7];
    const float* b2   = (const float*)d_in[8];
    float* out = (float*)d_out;

    int* wsi = (int*)d_ws;
    unsigned short* feats_bf = (unsigned short*)(wsi + WS_FEATS_W);
    unsigned short* W1T      = (unsigned short*)(wsi + WS_W1T_W);
    unsigned short* W2T      = (unsigned short*)(wsi + WS_W2T_W);
    float*          b1e      = (float*)(wsi + WS_B1E_W);

    const int wblocks = (K1 * HIDDEN + HIDDEN * OUT_DIM + HIDDEN + 255) / 256;

    wcvt_kernel<<<wblocks, 256, 0, stream>>>(W1, W2, b1, glob, W1T, W2T, b1e);
    agg_kernel<<<2 * NBLK, AGG_T, 0, stream>>>(edge, rcv, snd, feats_bf);
    gemm12_kernel<<<(N_NODES + 63) / 64, 512, 0, stream>>>(
        feats_bf, node, W1T, b1e, W2T, b2, out);
}

// Round 8
// 382.269 us; speedup vs baseline: 2.0907x; 2.0907x over previous
//
#include <hip/hip_runtime.h>

#define N_NODES   100000
#define N_EDGES   1600000
#define EDGE_DIM  32
#define NODE_DIM  128
#define K1        192    // rec32 + send32 + node128 (glob folded into b1_eff)
#define HIDDEN    256
#define OUT_DIM   128
#define NCNT      (2 * N_NODES)
#define SCAN_BLK  1024
#define NSCAN     ((NCNT + SCAN_BLK - 1) / SCAN_BLK)   // 196

// histogram partition params
#define RNG    32768            // nodes per range (u32 counters -> 128 KB LDS)
#define NRANGE 4                // ceil(100000 / 32768)
#define NSEG   32               // edge segments
#define SEGLEN (N_EDGES / NSEG) // 50000 (exact)

typedef float  f32x4   __attribute__((ext_vector_type(4)));
typedef short  short8  __attribute__((ext_vector_type(8)));
typedef unsigned short ushort8 __attribute__((ext_vector_type(8)));

// ---- ws layout (4-byte words), ~117.0 MB ----
// sorted u32[1.6M*16] = 102.4 MB; histogram replicas (33.6 MB) overlay its
// start and are fully consumed (scan1p) before fill_rows writes sorted.
#define B_SORT_W   0
#define B_FEATS_W  25600000                   // ushort[100000*64]
#define B_W1T_W    (B_FEATS_W + 3200000)      // ushort[256*192]
#define B_W2T_W    (B_W1T_W + 24576)          // ushort[128*256]
#define B_B1E_W    (B_W2T_W + 16384)          // float[256]
#define B_OFF_W    (B_B1E_W + 256)            // int[NCNT+1]
#define B_POS_W    (B_OFF_W + NCNT + 1)       // int[NCNT+1]
#define B_BSUM_W   (B_POS_W + NCNT + 1)       // int[NSCAN]

__device__ __forceinline__ unsigned short f2bf(float f) {
    unsigned int u = __float_as_uint(f);
    return (unsigned short)((u + 0x7fffu + ((u >> 16) & 1u)) >> 16);   // RNE
}

// ---------------------------------------------------------------------------
// Weight prep: W1T[n][k] (k<192), W2T[o][k], b1_eff = b1 + glob @ W1[192:224]
// ---------------------------------------------------------------------------
__global__ __launch_bounds__(256) void wcvt_kernel(
    const float* __restrict__ W1, const float* __restrict__ W2,
    const float* __restrict__ b1, const float* __restrict__ glob,
    unsigned short* __restrict__ W1T, unsigned short* __restrict__ W2T,
    float* __restrict__ b1e)
{
    int id = blockIdx.x * 256 + threadIdx.x;
    if (id < K1 * HIDDEN) {
        int n = id / K1, k = id - n * K1;
        W1T[id] = f2bf(W1[(size_t)k * HIDDEN + n]);
    } else if (id < K1 * HIDDEN + HIDDEN * OUT_DIM) {
        int id2 = id - K1 * HIDDEN;
        int o = id2 / HIDDEN, k = id2 - o * HIDDEN;
        W2T[id2] = f2bf(W2[(size_t)k * OUT_DIM + o]);
    } else if (id < K1 * HIDDEN + HIDDEN * OUT_DIM + HIDDEN) {
        int n = id - (K1 * HIDDEN + HIDDEN * OUT_DIM);
        float s = b1[n];
        #pragma unroll
        for (int j = 0; j < 32; ++j)
            s += glob[j] * W1[(size_t)(K1 + j) * HIDDEN + n];
        b1e[n] = s;
    }
}

// ---------------------------------------------------------------------------
// hist_part: block = (dir, range, seg). Private LDS u32[32768] histogram of
// this block's 50K-key slice (LDS atomics only), flushed as a coalesced
// replica. Zero global atomics.
// ---------------------------------------------------------------------------
__global__ __launch_bounds__(256) void hist_part_kernel(
    const int* __restrict__ rcv, const int* __restrict__ snd,
    unsigned int* __restrict__ rep)
{
    __shared__ unsigned int hcnt[RNG];   // 128 KB

    const int bid  = blockIdx.x;          // dir*128 + range*32 + seg
    const int tid  = threadIdx.x;
    const int dir  = bid >> 7;
    const int rr   = (bid >> 5) & 3;
    const int seg  = bid & 31;
    const int lo   = rr * RNG;
    const int* __restrict__ key = dir ? snd : rcv;

    for (int i = tid; i < RNG; i += 256) hcnt[i] = 0u;
    __syncthreads();

    const int kbase = seg * SEGLEN;
    for (int i4 = tid; i4 < SEGLEN / 4; i4 += 256) {
        int4 k4 = *(const int4*)&key[kbase + i4 * 4];
        #pragma unroll
        for (int j = 0; j < 4; ++j) {
            unsigned local = (unsigned)((&k4.x)[j] - lo);
            if (local < (unsigned)RNG) atomicAdd(&hcnt[local], 1u);
        }
    }
    __syncthreads();

    unsigned int* r = rep + ((size_t)bid << 15);
    for (int i = tid; i < RNG; i += 256) r[i] = hcnt[i];
}

// ---------------------------------------------------------------------------
// scan1p: fused replica-reduce + per-block exclusive scan -> off, block sums
// ---------------------------------------------------------------------------
__global__ __launch_bounds__(256) void scan1p_kernel(
    const unsigned int* __restrict__ rep, int* __restrict__ off,
    int* __restrict__ bsum)
{
    __shared__ int ts[256];
    const int t = threadIdx.x;
    const int base = blockIdx.x * SCAN_BLK + t * 4;

    int v[4], s = 0;
    #pragma unroll
    for (int j = 0; j < 4; ++j) {
        int idx = base + j;
        int c = 0;
        if (idx < NCNT) {
            int dir   = (idx >= N_NODES) ? 1 : 0;
            int n     = idx - dir * N_NODES;
            int rr    = n >> 15;
            int local = n & (RNG - 1);
            const unsigned int* r0 = rep + ((size_t)(dir * 128 + rr * 32) << 15) + local;
            #pragma unroll
            for (int sg = 0; sg < NSEG; ++sg) c += (int)r0[(size_t)sg << 15];
        }
        v[j] = c; s += c;
    }
    ts[t] = s;
    __syncthreads();
    for (int d = 1; d < 256; d <<= 1) {
        int x = (t >= d) ? ts[t - d] : 0;
        __syncthreads();
        ts[t] += x;
        __syncthreads();
    }
    int run = ts[t] - s;
    #pragma unroll
    for (int j = 0; j < 4; ++j) {
        int idx = base + j;
        if (idx < NCNT) off[idx] = run;
        run += v[j];
    }
    if (t == 255) bsum[blockIdx.x] = ts[255];
}

// ---------------------------------------------------------------------------
// Scan pass 2+3 fused
// ---------------------------------------------------------------------------
__global__ __launch_bounds__(256) void scan23_kernel(
    int* __restrict__ off, const int* __restrict__ bsum, int* __restrict__ pos)
{
    __shared__ int ts[256];
    __shared__ int sboff;
    const int t = threadIdx.x;
    int v = (t < NSCAN) ? bsum[t] : 0;
    ts[t] = v;
    __syncthreads();
    for (int d = 1; d < 256; d <<= 1) {
        int x = (t >= d) ? ts[t - d] : 0;
        __syncthreads();
        ts[t] += x;
        __syncthreads();
    }
    if (t == (int)blockIdx.x) sboff = ts[t] - v;
    __syncthreads();
    const int bo = sboff;

    const int base = blockIdx.x * SCAN_BLK + t * 4;
    #pragma unroll
    for (int j = 0; j < 4; ++j) {
        int idx = base + j;
        if (idx < NCNT) {
            int o = off[idx] + bo;
            off[idx] = o;
            pos[idx] = o;
        }
    }
    if (blockIdx.x == 0 && t == 0) off[NCNT] = 2 * N_EDGES;
}

// ---------------------------------------------------------------------------
// fill_rows: 16-lane group per edge; writes edge row as 32 bf16 (64B line)
// ---------------------------------------------------------------------------
__global__ __launch_bounds__(256) void fill_rows_kernel(
    const float* __restrict__ edge,
    const int*   __restrict__ key,
    int*         __restrict__ pos,
    unsigned int* __restrict__ sorted,
    int slot_base)
{
    int gid = blockIdx.x * 256 + threadIdx.x;
    int e = gid >> 4;
    if (e >= N_EDGES) return;
    int l = gid & 15;

    float2 v = *(const float2*)&edge[(size_t)e * EDGE_DIM + l * 2];
    unsigned int pk = (unsigned int)f2bf(v.x) | ((unsigned int)f2bf(v.y) << 16);

    int slot = 0;
    if (l == 0) slot = atomicAdd(&pos[key[e]], 1) - slot_base;
    slot = __shfl(slot, 0, 16);

    sorted[(size_t)slot * 16 + l] = pk;
}

// ---------------------------------------------------------------------------
// gather_rows: 16 lanes per node sum a contiguous run of sorted bf16 rows
// ---------------------------------------------------------------------------
__global__ __launch_bounds__(256) void gather_rows_kernel(
    const unsigned int* __restrict__ sorted,
    const int* __restrict__ off,
    unsigned short* __restrict__ feats_bf,
    int slot_base, int col_base)
{
    int gid = blockIdx.x * 256 + threadIdx.x;
    int n = gid >> 4;
    if (n >= N_NODES) return;
    int l = gid & 15;

    int s = off[n] - slot_base, e = off[n + 1] - slot_base;
    float ax = 0.f, ay = 0.f;
    for (int i = s; i < e; ++i) {
        unsigned int u = sorted[(size_t)i * 16 + l];
        ax += __uint_as_float(u << 16);
        ay += __uint_as_float(u & 0xffff0000u);
    }
    unsigned int pk = (unsigned int)f2bf(ax) | ((unsigned int)f2bf(ay) << 16);
    *(unsigned int*)&feats_bf[(size_t)n * 64 + col_base + l * 2] = pk;
}

// ---------------------------------------------------------------------------
// Fused GEMM1+GEMM2: 64 nodes/block, 512 threads (8 waves).
// Wave w: GEMM1 h-cols [32w,32w+32) (W1 frags in regs), GEMM2 out-cols
// [16w,16w+16) (W2 frags in regs). A and h in XOR-swizzled LDS (bf16).
// ---------------------------------------------------------------------------
__global__ __launch_bounds__(512) void gemm12_kernel(
    const unsigned short* __restrict__ feats_bf,
    const float* __restrict__ node,
    const unsigned short* __restrict__ W1T,
    const float* __restrict__ b1e,
    const unsigned short* __restrict__ W2T,
    const float* __restrict__ b2,
    float*       __restrict__ out)
{
    __shared__ unsigned short sA[64 * K1];       // 24 KB
    __shared__ unsigned short sH[64 * HIDDEN];   // 32 KB

    const int tid  = threadIdx.x;
    const int base = blockIdx.x * 64;

    for (int idx = tid; idx < 64 * 24; idx += 512) {
        int row = idx / 24;
        int c   = idx - row * 24;
        int g   = base + row; if (g >= N_NODES) g = N_NODES - 1;
        ushort8 r;
        if (c < 8) {
            r = *(const ushort8*)&feats_bf[(size_t)g * 64 + c * 8];
        } else {
            const float* np = &node[(size_t)g * NODE_DIM + (c - 8) * 8];
            float4 v0 = *(const float4*)np;
            float4 v1 = *(const float4*)(np + 4);
            r[0] = f2bf(v0.x); r[1] = f2bf(v0.y); r[2] = f2bf(v0.z); r[3] = f2bf(v0.w);
            r[4] = f2bf(v1.x); r[5] = f2bf(v1.y); r[6] = f2bf(v1.z); r[7] = f2bf(v1.w);
        }
        *(ushort8*)&sA[row * K1 + ((c ^ (row & 7)) << 3)] = r;
    }
    __syncthreads();

    const int wave = tid >> 6;
    const int lane = tid & 63;
    const int lm   = lane & 15;
    const int lk   = lane >> 4;

    short8 w1f[2][6];
    #pragma unroll
    for (int j = 0; j < 2; ++j) {
        int nt = 2 * wave + j;
        #pragma unroll
        for (int k = 0; k < 6; ++k)
            w1f[j][k] = *(const short8*)&W1T[(size_t)(nt * 16 + lm) * K1 + k * 32 + lk * 8];
    }

    f32x4 acc1[4][2];
    {
        float bv0 = b1e[(2 * wave) * 16 + lm];
        float bv1 = b1e[(2 * wave + 1) * 16 + lm];
        #pragma unroll
        for (int m = 0; m < 4; ++m) {
            acc1[m][0] = (f32x4){bv0, bv0, bv0, bv0};
            acc1[m][1] = (f32x4){bv1, bv1, bv1, bv1};
        }
    }

    #pragma unroll
    for (int k = 0; k < 6; ++k) {
        #pragma unroll
        for (int m = 0; m < 4; ++m) {
            int row   = m * 16 + lm;
            int chunk = k * 4 + lk;
            short8 af = *(const short8*)&sA[row * K1 + ((chunk ^ (row & 7)) << 3)];
            acc1[m][0] = __builtin_amdgcn_mfma_f32_16x16x32_bf16(af, w1f[0][k], acc1[m][0], 0, 0, 0);
            acc1[m][1] = __builtin_amdgcn_mfma_f32_16x16x32_bf16(af, w1f[1][k], acc1[m][1], 0, 0, 0);
        }
    }

    #pragma unroll
    for (int m = 0; m < 4; ++m) {
        #pragma unroll
        for (int j = 0; j < 2; ++j) {
            int col   = (2 * wave + j) * 16 + lm;
            int chunk = col >> 3;
            int cin   = col & 7;
            #pragma unroll
            for (int r = 0; r < 4; ++r) {
                int rowl = m * 16 + lk * 4 + r;
                float v = fmaxf(acc1[m][j][r], 0.0f);
                sH[rowl * HIDDEN + ((chunk ^ (rowl & 7)) << 3) + cin] = f2bf(v);
            }
        }
    }

    short8 w2f[8];
    #pragma unroll
    for (int k = 0; k < 8; ++k)
        w2f[k] = *(const short8*)&W2T[(size_t)(wave * 16 + lm) * HIDDEN + k * 32 + lk * 8];

    f32x4 acc2[4];
    {
        float bv = b2[wave * 16 + lm];
        #pragma unroll
        for (int m = 0; m < 4; ++m) acc2[m] = (f32x4){bv, bv, bv, bv};
    }
    __syncthreads();

    #pragma unroll
    for (int k = 0; k < 8; ++k) {
        #pragma unroll
        for (int m = 0; m < 4; ++m) {
            int row   = m * 16 + lm;
            int chunk = k * 4 + lk;
            short8 hf = *(const short8*)&sH[row * HIDDEN + ((chunk ^ (row & 7)) << 3)];
            acc2[m] = __builtin_amdgcn_mfma_f32_16x16x32_bf16(hf, w2f[k], acc2[m], 0, 0, 0);
        }
    }

    #pragma unroll
    for (int m = 0; m < 4; ++m) {
        #pragma unroll
        for (int r = 0; r < 4; ++r) {
            int grow = base + m * 16 + lk * 4 + r;
            if (grow < N_NODES)
                out[(size_t)grow * OUT_DIM + wave * 16 + lm] = acc2[m][r];
        }
    }
}

extern "C" void kernel_launch(void* const* d_in, const int* in_sizes, int n_in,
                              void* d_out, int out_size, void* d_ws, size_t ws_size,
                              hipStream_t stream) {
    const float* edge = (const float*)d_in[0];
    const int*   snd  = (const int*)  d_in[1];
    const int*   rcv  = (const int*)  d_in[2];
    const float* node = (const float*)d_in[3];
    const float* glob = (const float*)d_in[4];
    const float* W1   = (const float*)d_in[5];
    const float* b1   = (const float*)d_in[6];
    const float* W2   = (const float*)d_in[7];
    const float* b2   = (const float*)d_in[8];
    float* out = (float*)d_out;

    int* wsi = (int*)d_ws;
    unsigned int*   sorted   = (unsigned int*)(wsi + B_SORT_W);
    unsigned int*   rep      = (unsigned int*)(wsi + B_SORT_W);   // overlay, consumed pre-fill
    unsigned short* feats_bf = (unsigned short*)(wsi + B_FEATS_W);
    unsigned short* W1T      = (unsigned short*)(wsi + B_W1T_W);
    unsigned short* W2T      = (unsigned short*)(wsi + B_W2T_W);
    float*          b1e      = (float*)(wsi + B_B1E_W);
    int* off  = wsi + B_OFF_W;
    int* pos  = wsi + B_POS_W;
    int* bsum = wsi + B_BSUM_W;

    const int wblocks = (K1 * HIDDEN + HIDDEN * OUT_DIM + HIDDEN + 255) / 256;

    wcvt_kernel     <<<wblocks, 256, 0, stream>>>(W1, W2, b1, glob, W1T, W2T, b1e);
    hist_part_kernel<<<2 * NRANGE * NSEG, 256, 0, stream>>>(rcv, snd, rep);
    scan1p_kernel   <<<NSCAN, 256, 0, stream>>>(rep, off, bsum);
    scan23_kernel   <<<NSCAN, 256, 0, stream>>>(off, bsum, pos);

    const int fb = (N_EDGES * 16) / 256;       // 100000
    const int gb = (N_NODES * 16 + 255) / 256; // 6250
    fill_rows_kernel  <<<fb, 256, 0, stream>>>(edge, rcv, pos, sorted, 0);
    gather_rows_kernel<<<gb, 256, 0, stream>>>(sorted, off, feats_bf, 0, 0);
    fill_rows_kernel  <<<fb, 256, 0, stream>>>(edge, snd, pos + N_NODES, sorted, N_EDGES);
    gather_rows_kernel<<<gb, 256, 0, stream>>>(sorted, off + N_NODES, feats_bf, N_EDGES, 32);

    gemm12_kernel<<<(N_NODES + 63) / 64, 512, 0, stream>>>(
        feats_bf, node, W1T, b1e, W2T, b2, out);
}